// Round 9
// baseline (160.094 us; speedup 1.0000x reference)
//
#include <hip/hip_runtime.h>
#include <hip/hip_bf16.h>

// Problem constants (fixed by setup_inputs): Na=Nb=200000, Da=Db=64, S=256.
#define NKEYS   (1 << 24)          // 256^3 possible locations
#define NW      (NKEYS / 32)       // 524288 32-bit presence words (2 MB)
#define TPB     256
#define NBLK    512                // scan blocks (1024 words each)
#define GSBLK   2048               // grid-stride blocks for big kernels (8/CU x 256 CU)
#define MAXN    400000             // Na + Nb

typedef float        f32x4 __attribute__((ext_vector_type(4)));
typedef unsigned int u32x4 __attribute__((ext_vector_type(4)));
typedef int          i32x4 __attribute__((ext_vector_type(4)));

// Device-global scratch. Re-initialized every call (deterministic).
__device__ unsigned int g_bits[NW];        // presence bitmask per key
__device__ unsigned int g_wordPrefix[NW];  // exclusive rank base per 32-key word
__device__ unsigned int g_blockSums[NBLK]; // per-block popcount -> exclusive base
__device__ unsigned int g_doneCounter;
__device__ int          g_winner_a[MAXN];  // per-unique-slot winning a-row (max local index)
__device__ int          g_winner_b[MAXN];  // per-unique-slot winning b-row (max local index)
__device__ unsigned int g_rank[MAXN];      // rank of each input row (written by reverse)

// ---------------------------------------------------------------- init (grid-stride):
// zero bit table, winner tables = -1, out_loc fully prefilled with -1
// (prefix_loc later overwrites rows [0,U) — subsequent dispatch, no race).
__global__ void k_init(float* __restrict__ out_loc, int N) {
    int tid = blockIdx.x * blockDim.x + threadIdx.x;
    int gs  = gridDim.x * blockDim.x;
    for (int i = tid; i < NW / 4; i += gs)
        reinterpret_cast<u32x4*>(g_bits)[i] = (u32x4)(0u);
    for (int i = tid; i < MAXN / 4; i += gs) {
        reinterpret_cast<i32x4*>(g_winner_a)[i] = (i32x4)(-1);
        reinterpret_cast<i32x4*>(g_winner_b)[i] = (i32x4)(-1);
    }
    for (int i = tid; i < N * 3; i += gs) out_loc[i] = -1.0f;
    if (tid == 0) g_doneCounter = 0u;
}

// ---------------------------------------------------------------- mark presence (4 rows / thread)
__global__ void k_mark4(const int* __restrict__ a_loc, const int* __restrict__ b_loc,
                        int nA4, int n4) {
    int j = blockIdx.x * blockDim.x + threadIdx.x;
    if (j >= n4) return;
    const uint4* src = (j < nA4) ? reinterpret_cast<const uint4*>(a_loc)
                                 : reinterpret_cast<const uint4*>(b_loc);
    int jj = (j < nA4) ? j : j - nA4;
    uint4 q0 = src[jj * 3], q1 = src[jj * 3 + 1], q2 = src[jj * 3 + 2];
    int k0 = (q0.x << 16) | (q0.y << 8) | q0.z;
    int k1 = (q0.w << 16) | (q1.x << 8) | q1.y;
    int k2 = (q1.z << 16) | (q1.w << 8) | q2.x;
    int k3 = (q2.y << 16) | (q2.z << 8) | q2.w;
    atomicOr(&g_bits[k0 >> 5], 1u << (k0 & 31));
    atomicOr(&g_bits[k1 >> 5], 1u << (k1 & 31));
    atomicOr(&g_bits[k2 >> 5], 1u << (k2 & 31));
    atomicOr(&g_bits[k3 >> 5], 1u << (k3 & 31));
}

// ---------------------------------------------------------------- reduce + scan (last-block-done)
__global__ void k_reduce_scan() {
    __shared__ unsigned int s[TPB];
    __shared__ unsigned int isLast;
    int b = blockIdx.x, t = threadIdx.x;
    u32x4 w = reinterpret_cast<const u32x4*>(g_bits)[b * TPB + t];
    s[t] = __popc(w.x) + __popc(w.y) + __popc(w.z) + __popc(w.w);
    __syncthreads();
    for (int off = TPB / 2; off > 0; off >>= 1) {
        if (t < off) s[t] += s[t + off];
        __syncthreads();
    }
    if (t == 0) {
        g_blockSums[b] = s[0];
        __threadfence();
        isLast = (atomicAdd(&g_doneCounter, 1u) == NBLK - 1) ? 1u : 0u;
    }
    __syncthreads();
    if (isLast) {
        __threadfence();
        unsigned int v0 = g_blockSums[t * 2], v1 = g_blockSums[t * 2 + 1];
        unsigned int pair = v0 + v1;
        s[t] = pair;
        __syncthreads();
        for (int off = 1; off < TPB; off <<= 1) {
            unsigned int u = (t >= off) ? s[t - off] : 0u;
            __syncthreads();
            s[t] += u;
            __syncthreads();
        }
        unsigned int excl = s[t] - pair;
        g_blockSums[t * 2]     = excl;
        g_blockSums[t * 2 + 1] = excl + v0;
    }
}

// ---------------------------------------------------------------- word prefixes + sorted unique locations
__global__ void k_prefix_loc(float* __restrict__ out_loc) {
    __shared__ unsigned int s[TPB];
    int b = blockIdx.x, t = threadIdx.x;
    int wi = b * TPB + t;
    int w0 = wi * 4;
    u32x4 wv = reinterpret_cast<const u32x4*>(g_bits)[wi];
    unsigned int wlocal[4] = { wv.x, wv.y, wv.z, wv.w };
    unsigned int cnt = __popc(wv.x) + __popc(wv.y) + __popc(wv.z) + __popc(wv.w);
    s[t] = cnt;
    __syncthreads();
    for (int off = 1; off < TPB; off <<= 1) {
        unsigned int u = (t >= off) ? s[t - off] : 0u;
        __syncthreads();
        s[t] += u;
        __syncthreads();
    }
    unsigned int r = g_blockSums[b] + s[t] - cnt;
#pragma unroll
    for (int j = 0; j < 4; ++j) {
        unsigned int bits = wlocal[j];
        g_wordPrefix[w0 + j] = r;
        while (bits) {
            int bit = __ffs(bits) - 1; bits &= bits - 1;
            int key = ((w0 + j) << 5) | bit;
            float* p = out_loc + (size_t)r * 3;
            p[0] = (float)(key >> 16); p[1] = (float)((key >> 8) & 255); p[2] = (float)(key & 255);
            ++r;
        }
    }
}

// ---------------------------------------------------------------- inverse + winners + rank store
__global__ void k_reverse4(const int* __restrict__ a_loc, const int* __restrict__ b_loc,
                           int nA4, int n4, int Na) {
    int j = blockIdx.x * blockDim.x + threadIdx.x;
    if (j >= n4) return;
    bool isA = (j < nA4);
    const uint4* src = isA ? reinterpret_cast<const uint4*>(a_loc)
                           : reinterpret_cast<const uint4*>(b_loc);
    int jj = isA ? j : j - nA4;
    uint4 q0 = src[jj * 3], q1 = src[jj * 3 + 1], q2 = src[jj * 3 + 2];
    int key[4];
    key[0] = (q0.x << 16) | (q0.y << 8) | q0.z;
    key[1] = (q0.w << 16) | (q1.x << 8) | q1.y;
    key[2] = (q1.z << 16) | (q1.w << 8) | q2.x;
    key[3] = (q2.y << 16) | (q2.z << 8) | q2.w;
    int* winner = isA ? g_winner_a : g_winner_b;
    int base = jj * 4;                                      // local row index base
    int gbase = isA ? base : (Na + base);                   // global row index base
    u32x4 rv;
#pragma unroll
    for (int k = 0; k < 4; ++k) {
        int kk = key[k];
        unsigned int word = g_bits[kk >> 5];
        unsigned int r = g_wordPrefix[kk >> 5] + __popc(word & ((1u << (kk & 31)) - 1u));
        atomicMax(&winner[r], base + k);                    // last (max) row index wins (XLA order)
        ((unsigned int*)&rv)[k] = r;
    }
    reinterpret_cast<u32x4*>(g_rank)[gbase >> 2] = rv;      // coalesced rank store
}

// scalar fallbacks (only used if Na or Nb not divisible by 4)
__global__ void k_mark1(const int* __restrict__ a_loc, const int* __restrict__ b_loc,
                        int Na, int N) {
    int i = blockIdx.x * blockDim.x + threadIdx.x;
    if (i >= N) return;
    const int* p = (i < Na) ? (a_loc + (size_t)i * 3) : (b_loc + (size_t)(i - Na) * 3);
    int key = (p[0] << 16) | (p[1] << 8) | p[2];
    atomicOr(&g_bits[key >> 5], 1u << (key & 31));
}
__global__ void k_reverse1(const int* __restrict__ a_loc, const int* __restrict__ b_loc,
                           int Na, int N) {
    int i = blockIdx.x * blockDim.x + threadIdx.x;
    if (i >= N) return;
    const int* p = (i < Na) ? (a_loc + (size_t)i * 3) : (b_loc + (size_t)(i - Na) * 3);
    int key = (p[0] << 16) | (p[1] << 8) | p[2];
    unsigned int word = g_bits[key >> 5];
    unsigned int r = g_wordPrefix[key >> 5] + __popc(word & ((1u << (key & 31)) - 1u));
    if (i < Na) atomicMax(&g_winner_a[r], i);
    else        atomicMax(&g_winner_b[r], i - Na);
    g_rank[i] = r;
}

// ---------------------------------------------------------------- zero + scatter (grid-stride)
// idx in [0, N*8): zero-role — slot u, half h, 64B chunk c; zero halves with no winner
//   (covers absent halves AND padding rows u>=U).
// idx in [N*8, N*12): scatter-role — row i, 64B chunk c; winners stream-read their
//   feature row (sequential) and write their 256B half-row at out_feat[rank] (random).
__global__ void k_zero_scatter(const float* __restrict__ a_feat, const float* __restrict__ b_feat,
                               float* __restrict__ out_feat, int Na, int N) {
    int tid = blockIdx.x * blockDim.x + threadIdx.x;
    int gs  = gridDim.x * blockDim.x;
    int total = N * 12;
    for (int idx = tid; idx < total; idx += gs) {
        if (idx < N * 8) {
            int u = idx >> 3;
            int h = (idx >> 2) & 1;
            int c = idx & 3;
            int w = h ? g_winner_b[u] : g_winner_a[u];
            if (w < 0) {
                float* dst = out_feat + (size_t)u * 128 + h * 64 + c * 16;
                f32x4 z = (f32x4)(0.f);
                *reinterpret_cast<f32x4*>(dst)      = z;
                *reinterpret_cast<f32x4*>(dst + 4)  = z;
                *reinterpret_cast<f32x4*>(dst + 8)  = z;
                *reinterpret_cast<f32x4*>(dst + 12) = z;
            }
        } else {
            int sidx = idx - N * 8;                         // [0, N*4)
            int i = sidx >> 2;                              // global row
            int c = sidx & 3;                               // 16-float chunk
            bool isA = (i < Na);
            int ii = isA ? i : i - Na;                      // local row
            unsigned int r = g_rank[i];
            int w = isA ? g_winner_a[r] : g_winner_b[r];
            if (w != ii) continue;                          // a duplicate that lost
            const float* src = (isA ? a_feat : b_feat) + (size_t)ii * 64 + c * 16;
            f32x4 v0 = *reinterpret_cast<const f32x4*>(src);
            f32x4 v1 = *reinterpret_cast<const f32x4*>(src + 4);
            f32x4 v2 = *reinterpret_cast<const f32x4*>(src + 8);
            f32x4 v3 = *reinterpret_cast<const f32x4*>(src + 12);
            float* dst = out_feat + (size_t)r * 128 + (isA ? 0 : 64) + c * 16;
            *reinterpret_cast<f32x4*>(dst)      = v0;
            *reinterpret_cast<f32x4*>(dst + 4)  = v1;
            *reinterpret_cast<f32x4*>(dst + 8)  = v2;
            *reinterpret_cast<f32x4*>(dst + 12) = v3;
        }
    }
}

// ---------------------------------------------------------------- launch
extern "C" void kernel_launch(void* const* d_in, const int* in_sizes, int n_in,
                              void* d_out, int out_size, void* d_ws, size_t ws_size,
                              hipStream_t stream) {
    const int*   a_loc  = (const int*)  d_in[0];
    const float* a_feat = (const float*)d_in[1];
    const int*   b_loc  = (const int*)  d_in[2];
    const float* b_feat = (const float*)d_in[3];

    const int Na = in_sizes[0] / 3;
    const int Nb = in_sizes[2] / 3;
    const int N  = Na + Nb;                      // 400000

    float* out_loc  = (float*)d_out;             // N*3 floats (unique_locations, -1 padded)
    float* out_feat = out_loc + (size_t)N * 3;   // N*128 floats

    k_init<<<GSBLK, TPB, 0, stream>>>(out_loc, N);

    if ((Na % 4) == 0 && (Nb % 4) == 0) {
        int nA4 = Na / 4, n4 = (Na + Nb) / 4;
        k_mark4<<<(n4 + TPB - 1) / TPB, TPB, 0, stream>>>(a_loc, b_loc, nA4, n4);
        k_reduce_scan<<<NBLK, TPB, 0, stream>>>();
        k_prefix_loc<<<NBLK, TPB, 0, stream>>>(out_loc);
        k_reverse4<<<(n4 + TPB - 1) / TPB, TPB, 0, stream>>>(a_loc, b_loc, nA4, n4, Na);
    } else {
        k_mark1<<<(N + TPB - 1) / TPB, TPB, 0, stream>>>(a_loc, b_loc, Na, N);
        k_reduce_scan<<<NBLK, TPB, 0, stream>>>();
        k_prefix_loc<<<NBLK, TPB, 0, stream>>>(out_loc);
        k_reverse1<<<(N + TPB - 1) / TPB, TPB, 0, stream>>>(a_loc, b_loc, Na, N);
    }

    k_zero_scatter<<<GSBLK, TPB, 0, stream>>>(a_feat, b_feat, out_feat, Na, N);
}

// Round 10
// 152.340 us; speedup vs baseline: 1.0509x; 1.0509x over previous
//
#include <hip/hip_runtime.h>
#include <hip/hip_bf16.h>

// Problem constants (fixed by setup_inputs): Na=Nb=200000, Da=Db=64, S=256.
#define NKEYS   (1 << 24)          // 256^3 possible locations
#define NW      (NKEYS / 32)       // 524288 32-bit presence words (2 MB)
#define TPB     256
#define NBLK    512                // scan blocks (1024 words each)
#define MAXN    400000             // Na + Nb

typedef float        f32x4 __attribute__((ext_vector_type(4)));
typedef unsigned int u32x4 __attribute__((ext_vector_type(4)));
typedef int          i32x4 __attribute__((ext_vector_type(4)));

// Device-global scratch. Re-initialized every call (deterministic).
__device__ unsigned int g_bits[NW];        // presence bitmask per key
__device__ unsigned int g_wordPrefix[NW];  // exclusive rank base per 32-key word
__device__ unsigned int g_blockSums[NBLK]; // per-block popcount -> exclusive base
__device__ unsigned int g_doneCounter;
__device__ int          g_winner_a[MAXN];  // per-unique-slot winning a-row (max local index)
__device__ int          g_winner_b[MAXN];  // per-unique-slot winning b-row (max local index)
__device__ unsigned int g_rank[MAXN];      // rank of each input row (written by reverse)

// ---------------------------------------------------------------- init: zero bit table
__global__ void k_init() {
    int i = blockIdx.x * blockDim.x + threadIdx.x;          // NW/4 threads
    reinterpret_cast<u32x4*>(g_bits)[i] = (u32x4)(0u);
    if (i == 0) g_doneCounter = 0u;
}

// ---------------------------------------------------------------- mark presence (4 rows / thread)
__global__ void k_mark4(const int* __restrict__ a_loc, const int* __restrict__ b_loc,
                        int nA4, int n4) {
    int j = blockIdx.x * blockDim.x + threadIdx.x;
    if (j >= n4) return;
    const uint4* src = (j < nA4) ? reinterpret_cast<const uint4*>(a_loc)
                                 : reinterpret_cast<const uint4*>(b_loc);
    int jj = (j < nA4) ? j : j - nA4;
    uint4 q0 = src[jj * 3], q1 = src[jj * 3 + 1], q2 = src[jj * 3 + 2];
    int k0 = (q0.x << 16) | (q0.y << 8) | q0.z;
    int k1 = (q0.w << 16) | (q1.x << 8) | q1.y;
    int k2 = (q1.z << 16) | (q1.w << 8) | q2.x;
    int k3 = (q2.y << 16) | (q2.z << 8) | q2.w;
    atomicOr(&g_bits[k0 >> 5], 1u << (k0 & 31));
    atomicOr(&g_bits[k1 >> 5], 1u << (k1 & 31));
    atomicOr(&g_bits[k2 >> 5], 1u << (k2 & 31));
    atomicOr(&g_bits[k3 >> 5], 1u << (k3 & 31));
}

// ---------------------------------------------------------------- reduce + scan (last-block-done)
__global__ void k_reduce_scan() {
    __shared__ unsigned int s[TPB];
    __shared__ unsigned int isLast;
    int b = blockIdx.x, t = threadIdx.x;
    u32x4 w = reinterpret_cast<const u32x4*>(g_bits)[b * TPB + t];
    s[t] = __popc(w.x) + __popc(w.y) + __popc(w.z) + __popc(w.w);
    __syncthreads();
    for (int off = TPB / 2; off > 0; off >>= 1) {
        if (t < off) s[t] += s[t + off];
        __syncthreads();
    }
    if (t == 0) {
        g_blockSums[b] = s[0];
        __threadfence();
        isLast = (atomicAdd(&g_doneCounter, 1u) == NBLK - 1) ? 1u : 0u;
    }
    __syncthreads();
    if (isLast) {
        __threadfence();
        unsigned int v0 = g_blockSums[t * 2], v1 = g_blockSums[t * 2 + 1];
        unsigned int pair = v0 + v1;
        s[t] = pair;
        __syncthreads();
        for (int off = 1; off < TPB; off <<= 1) {
            unsigned int u = (t >= off) ? s[t - off] : 0u;
            __syncthreads();
            s[t] += u;
            __syncthreads();
        }
        unsigned int excl = s[t] - pair;
        g_blockSums[t * 2]     = excl;
        g_blockSums[t * 2 + 1] = excl + v0;
    }
}

// ---------------------------------------------------------------- word prefixes + sorted unique
// locations + winner-table init + -1 tail fill (last block knows U)
__global__ void k_prefix_loc(float* __restrict__ out_loc, int N) {
    __shared__ unsigned int s[TPB];
    __shared__ unsigned int sU;
    int b = blockIdx.x, t = threadIdx.x;
    int wi = b * TPB + t;
    if (wi < MAXN / 4) {
        reinterpret_cast<i32x4*>(g_winner_a)[wi] = (i32x4)(-1);
        reinterpret_cast<i32x4*>(g_winner_b)[wi] = (i32x4)(-1);
    }
    int w0 = wi * 4;
    u32x4 wv = reinterpret_cast<const u32x4*>(g_bits)[wi];
    unsigned int wlocal[4] = { wv.x, wv.y, wv.z, wv.w };
    unsigned int cnt = __popc(wv.x) + __popc(wv.y) + __popc(wv.z) + __popc(wv.w);
    s[t] = cnt;
    __syncthreads();
    for (int off = 1; off < TPB; off <<= 1) {
        unsigned int u = (t >= off) ? s[t - off] : 0u;
        __syncthreads();
        s[t] += u;
        __syncthreads();
    }
    unsigned int r = g_blockSums[b] + s[t] - cnt;
#pragma unroll
    for (int j = 0; j < 4; ++j) {
        unsigned int bits = wlocal[j];
        g_wordPrefix[w0 + j] = r;
        while (bits) {
            int bit = __ffs(bits) - 1; bits &= bits - 1;
            int key = ((w0 + j) << 5) | bit;
            float* p = out_loc + (size_t)r * 3;
            p[0] = (float)(key >> 16); p[1] = (float)((key >> 8) & 255); p[2] = (float)(key & 255);
            ++r;
        }
    }
    if (b == NBLK - 1) {
        if (t == TPB - 1) sU = r;                           // total unique count
        __syncthreads();
        for (int i = (int)sU * 3 + t; i < N * 3; i += TPB) out_loc[i] = -1.0f;
    }
}

// ---------------------------------------------------------------- inverse + winners + rank store
__global__ void k_reverse4(const int* __restrict__ a_loc, const int* __restrict__ b_loc,
                           int nA4, int n4, int Na) {
    int j = blockIdx.x * blockDim.x + threadIdx.x;
    if (j >= n4) return;
    bool isA = (j < nA4);
    const uint4* src = isA ? reinterpret_cast<const uint4*>(a_loc)
                           : reinterpret_cast<const uint4*>(b_loc);
    int jj = isA ? j : j - nA4;
    uint4 q0 = src[jj * 3], q1 = src[jj * 3 + 1], q2 = src[jj * 3 + 2];
    int key[4];
    key[0] = (q0.x << 16) | (q0.y << 8) | q0.z;
    key[1] = (q0.w << 16) | (q1.x << 8) | q1.y;
    key[2] = (q1.z << 16) | (q1.w << 8) | q2.x;
    key[3] = (q2.y << 16) | (q2.z << 8) | q2.w;
    int* winner = isA ? g_winner_a : g_winner_b;
    int base = jj * 4;                                      // local row index base
    int gbase = isA ? base : (Na + base);                   // global row index base
    u32x4 rv;
#pragma unroll
    for (int k = 0; k < 4; ++k) {
        int kk = key[k];
        unsigned int word = g_bits[kk >> 5];
        unsigned int r = g_wordPrefix[kk >> 5] + __popc(word & ((1u << (kk & 31)) - 1u));
        atomicMax(&winner[r], base + k);                    // last (max) row index wins (XLA order)
        ((unsigned int*)&rv)[k] = r;
    }
    reinterpret_cast<u32x4*>(g_rank)[gbase >> 2] = rv;      // coalesced rank store
}

// scalar fallbacks (only used if Na or Nb not divisible by 4)
__global__ void k_mark1(const int* __restrict__ a_loc, const int* __restrict__ b_loc,
                        int Na, int N) {
    int i = blockIdx.x * blockDim.x + threadIdx.x;
    if (i >= N) return;
    const int* p = (i < Na) ? (a_loc + (size_t)i * 3) : (b_loc + (size_t)(i - Na) * 3);
    int key = (p[0] << 16) | (p[1] << 8) | p[2];
    atomicOr(&g_bits[key >> 5], 1u << (key & 31));
}
__global__ void k_reverse1(const int* __restrict__ a_loc, const int* __restrict__ b_loc,
                           int Na, int N) {
    int i = blockIdx.x * blockDim.x + threadIdx.x;
    if (i >= N) return;
    const int* p = (i < Na) ? (a_loc + (size_t)i * 3) : (b_loc + (size_t)(i - Na) * 3);
    int key = (p[0] << 16) | (p[1] << 8) | p[2];
    unsigned int word = g_bits[key >> 5];
    unsigned int r = g_wordPrefix[key >> 5] + __popc(word & ((1u << (key & 31)) - 1u));
    if (i < Na) atomicMax(&g_winner_a[r], i);
    else        atomicMax(&g_winner_b[r], i - Na);
    g_rank[i] = r;
}

// ---------------------------------------------------------------- zero + scatter (one dispatch)
// Blocks [0, zblk): zero-role. One thread per (slot, half, 64B chunk): N*8 threads.
//   winner<0 covers both "half absent" and padding rows u>=U -> zero those halves.
// Blocks [zblk, ...): scatter-role. One thread per (row, 64B chunk): N*4 threads.
//   Sequential feature reads (coalesced stream); winning rows write their 256B
//   half-row to out_feat[rank] (random 256B writes, fire-and-forget).
__global__ void k_zero_scatter(const float* __restrict__ a_feat, const float* __restrict__ b_feat,
                               float* __restrict__ out_feat, int Na, int N, int zblk) {
    int b = blockIdx.x, t = threadIdx.x;
    if (b < zblk) {
        int idx = b * TPB + t;                              // [0, N*8)
        if (idx >= N * 8) return;
        int u = idx >> 3;
        int h = (idx >> 2) & 1;
        int c = idx & 3;
        int w = h ? g_winner_b[u] : g_winner_a[u];
        if (w < 0) {
            float* dst = out_feat + (size_t)u * 128 + h * 64 + c * 16;
            f32x4 z = (f32x4)(0.f);
            *reinterpret_cast<f32x4*>(dst)      = z;
            *reinterpret_cast<f32x4*>(dst + 4)  = z;
            *reinterpret_cast<f32x4*>(dst + 8)  = z;
            *reinterpret_cast<f32x4*>(dst + 12) = z;
        }
    } else {
        int idx = (b - zblk) * TPB + t;                     // [0, N*4)
        if (idx >= N * 4) return;
        int i = idx >> 2;                                   // global row
        int c = idx & 3;                                    // 16-float chunk
        bool isA = (i < Na);
        int ii = isA ? i : i - Na;                          // local row
        unsigned int r = g_rank[i];
        int w = isA ? g_winner_a[r] : g_winner_b[r];
        if (w != ii) return;                                // a duplicate that lost
        const float* src = (isA ? a_feat : b_feat) + (size_t)ii * 64 + c * 16;
        f32x4 v0 = *reinterpret_cast<const f32x4*>(src);
        f32x4 v1 = *reinterpret_cast<const f32x4*>(src + 4);
        f32x4 v2 = *reinterpret_cast<const f32x4*>(src + 8);
        f32x4 v3 = *reinterpret_cast<const f32x4*>(src + 12);
        float* dst = out_feat + (size_t)r * 128 + (isA ? 0 : 64) + c * 16;
        *reinterpret_cast<f32x4*>(dst)      = v0;
        *reinterpret_cast<f32x4*>(dst + 4)  = v1;
        *reinterpret_cast<f32x4*>(dst + 8)  = v2;
        *reinterpret_cast<f32x4*>(dst + 12) = v3;
    }
}

// ---------------------------------------------------------------- launch
extern "C" void kernel_launch(void* const* d_in, const int* in_sizes, int n_in,
                              void* d_out, int out_size, void* d_ws, size_t ws_size,
                              hipStream_t stream) {
    const int*   a_loc  = (const int*)  d_in[0];
    const float* a_feat = (const float*)d_in[1];
    const int*   b_loc  = (const int*)  d_in[2];
    const float* b_feat = (const float*)d_in[3];

    const int Na = in_sizes[0] / 3;
    const int Nb = in_sizes[2] / 3;
    const int N  = Na + Nb;                      // 400000

    float* out_loc  = (float*)d_out;             // N*3 floats (unique_locations, -1 padded)
    float* out_feat = out_loc + (size_t)N * 3;   // N*128 floats

    k_init<<<NW / 4 / TPB, TPB, 0, stream>>>();

    if ((Na % 4) == 0 && (Nb % 4) == 0) {
        int nA4 = Na / 4, n4 = (Na + Nb) / 4;
        k_mark4<<<(n4 + TPB - 1) / TPB, TPB, 0, stream>>>(a_loc, b_loc, nA4, n4);
        k_reduce_scan<<<NBLK, TPB, 0, stream>>>();
        k_prefix_loc<<<NBLK, TPB, 0, stream>>>(out_loc, N);
        k_reverse4<<<(n4 + TPB - 1) / TPB, TPB, 0, stream>>>(a_loc, b_loc, nA4, n4, Na);
    } else {
        k_mark1<<<(N + TPB - 1) / TPB, TPB, 0, stream>>>(a_loc, b_loc, Na, N);
        k_reduce_scan<<<NBLK, TPB, 0, stream>>>();
        k_prefix_loc<<<NBLK, TPB, 0, stream>>>(out_loc, N);
        k_reverse1<<<(N + TPB - 1) / TPB, TPB, 0, stream>>>(a_loc, b_loc, Na, N);
    }

    int zblk = (N * 8 + TPB - 1) / TPB;          // zero-role blocks
    int sblk = (N * 4 + TPB - 1) / TPB;          // scatter-role blocks
    k_zero_scatter<<<zblk + sblk, TPB, 0, stream>>>(a_feat, b_feat, out_feat, Na, N, zblk);
}